// Round 12
// baseline (18.129 us; speedup 1.0000x reference)
//
#include <hip/hip_runtime.h>
#include <hip/hip_fp16.h>

#define KN 4096
#define NSAMP 16384

// d_ws layout:
//   cf16  : uint2[16384] @ 0       (128 KB) 4xfp16 coeffs/neuron (layers 1-3 used)
//   pidx  : uint [16384] @ 131072  ( 64 KB) ia | (ib<<16)
//   h0f16 : half [65536] @ 196608  (128 KB) layer-0 out, [pat][k], fp16
//   pats  : uchar[16384] @ 327680  ( 16 KB) p0 pattern byte per sample
//   maskp : uint [64]    @ 344064  (256 B)  per-prep-block OR of (1<<p0)

__device__ __forceinline__ void softmax16(const float* __restrict__ wp,
                                          float& c0, float& ca, float& cb, float& cab) {
    const float4* wr = (const float4*)wp;
    float4 v0 = wr[0], v1 = wr[1], v2 = wr[2], v3 = wr[3];
    // weights ~ N(0,1): expf cannot overflow -> skip max-subtract.
    float e0 = __expf(v0.x), e1 = __expf(v0.y), e2 = __expf(v0.z), e3 = __expf(v0.w);
    float e4 = __expf(v1.x), e5 = __expf(v1.y), e6 = __expf(v1.z), e7 = __expf(v1.w);
    float e8 = __expf(v2.x), e9 = __expf(v2.y), e10 = __expf(v2.z), e11 = __expf(v2.w);
    float e12 = __expf(v3.x), e13 = __expf(v3.y), e14 = __expf(v3.z), e15 = __expf(v3.w);
    float s = ((e0 + e1) + (e2 + e3)) + ((e4 + e5) + (e6 + e7))
            + ((e8 + e9) + (e10 + e11)) + ((e12 + e13) + (e14 + e15));
    float can  = ((e2 + e3) + (e6 + e7)) - ((e8 + e9) + (e12 + e13));
    float cbn  = ((e4 + e5) + (e6 + e7)) - ((e8 + e9) + (e10 + e11));
    float cabn = (e1 - e2) - (e4 + e7) - 2.0f * e6 + (e8 + e11) + 2.0f * e9
               + (e13 - e14);
    float c0n  = ((e8 + e9) + (e10 + e11)) + ((e12 + e13) + (e14 + e15));
    float inv = 1.0f / s;
    c0 = c0n * inv; ca = can * inv; cb = cbn * inv; cab = cabn * inv;
}

// ---------------- Node 1: prep (128 blocks x 256) ----------------
// bid [0,48):   layers 1-3 descs: fp16x4 coeffs + packed indices (1 softmax/neuron)
// bid [48,64):  layer-0: 1 softmax per neuron -> all 16 pattern outputs (fp16)
// bid [64,128): pats[n] + per-block pattern-occupancy mask
__global__ __launch_bounds__(256) void prep(
    const float* __restrict__ w0, const float* __restrict__ wsG,
    const int* __restrict__ ia0, const int* __restrict__ ib0,
    const int* __restrict__ ia, const int* __restrict__ ib,
    const float* __restrict__ x,
    uint2* __restrict__ cf16, unsigned* __restrict__ pidx,
    __half* __restrict__ h0f16, unsigned char* __restrict__ pats,
    unsigned* __restrict__ maskp) {
    const int bid = blockIdx.x, tid = threadIdx.x;
    if (bid < 48) {
        int g = KN + bid * 256 + tid;          // g in [4096, 16384)
        int layer = g >> 12;                   // 1..3
        int k = g & 4095;
        float c0, ca, cb, cab;
        softmax16(wsG + ((size_t)(layer - 1) * KN + k) * 16, c0, ca, cb, cab);
        __half2 p01 = __floats2half2_rn(c0, ca);
        __half2 p23 = __floats2half2_rn(cb, cab);
        uint2 c;
        c.x = *(unsigned*)&p01;
        c.y = *(unsigned*)&p23;
        cf16[g] = c;
        pidx[g] = (unsigned)ia[(layer - 1) * KN + k]
                | ((unsigned)ib[(layer - 1) * KN + k] << 16);
    } else if (bid < 64) {
        int k = (bid - 48) * 256 + tid;        // layer-0 neuron
        float c0, ca, cb, cab;
        softmax16(w0 + (size_t)k * 16, c0, ca, cb, cab);
        int A = ia0[k], B = ib0[k];
        #pragma unroll
        for (int pat = 0; pat < 16; ++pat) {
            float a = (float)((pat >> A) & 1);
            float b = (float)((pat >> B) & 1);
            h0f16[pat * KN + k] = __float2half(c0 + ca * a + cb * b + cab * (a * b));
        }
    } else {
        int n = (bid - 64) * 256 + tid;
        float2 xv = ((const float2*)x)[n];
        int p0 = (int)(xv.x > 0.0f) | ((int)(xv.y > 0.0f) << 1)
               | ((int)(-xv.x > 0.0f) << 2) | ((int)(-xv.y > 0.0f) << 3);
        pats[n] = (unsigned char)p0;
        // block OR-mask of patterns present (plain stores, rewritten each call)
        __shared__ unsigned sm[4];
        unsigned m = 1u << p0;
        #pragma unroll
        for (int off = 32; off > 0; off >>= 1) m |= __shfl_xor(m, off, 64);
        int wid = tid >> 6, lane = tid & 63;
        if (lane == 0) sm[wid] = m;
        __syncthreads();
        if (tid == 0) maskp[bid - 64] = sm[0] | sm[1] | sm[2] | sm[3];
    }
}

__device__ __forceinline__ float neuron2(uint2 c, float a, float b) {
    float2 c01 = __half22float2(*(__half2*)&c.x);   // (c0, ca)
    float2 c23 = __half22float2(*(__half2*)&c.y);   // (cb, cab)
    return c01.x + c01.y * a + c23.x * b + c23.y * (a * b);
}

// Slow-path helper (never taken in practice): full network eval for pattern pp.
__device__ void eval_full(int pp, const uint2* __restrict__ cf16,
                          const unsigned* __restrict__ pidx,
                          const __half* __restrict__ h0f16,
                          float* h0, float* h1, float* red, int tid,
                          float& r0, float& r1) {
    #pragma unroll
    for (int i = 0; i < 4; ++i) {
        int k = tid + i * 1024;
        h0[k] = __half2float(h0f16[pp * KN + k]);
    }
    __syncthreads();
    for (int l = 1; l <= 3; ++l) {
        const float* src = (l & 1) ? h0 : h1;
        float* dst = (l & 1) ? h1 : h0;
        #pragma unroll
        for (int i = 0; i < 4; ++i) {
            int k = tid + i * 1024;
            unsigned xi = pidx[l * KN + k];
            dst[k] = neuron2(cf16[l * KN + k], src[xi & 0xffff], src[xi >> 16]);
        }
        __syncthreads();
    }
    float s0 = h1[tid] + h1[tid + 1024];
    float s1 = h1[tid + 2048] + h1[tid + 3072];
    #pragma unroll
    for (int off = 32; off > 0; off >>= 1) {
        s0 += __shfl_down(s0, off, 64);
        s1 += __shfl_down(s1, off, 64);
    }
    int wid = tid >> 6, lane = tid & 63;
    if (lane == 0) { red[wid] = s0; red[16 + wid] = s1; }
    __syncthreads();
    if (tid == 0) {
        float t0 = 0.0f, t1 = 0.0f;
        #pragma unroll
        for (int wq = 0; wq < 16; ++wq) { t0 += red[wq]; t1 += red[16 + wq]; }
        red[32] = t0; red[33] = t1;
    }
    __syncthreads();
    r0 = red[32]; r1 = red[33];
    __syncthreads();
}

// ---------------- Node 2: per-pattern net (layers 1-3) + scatter ----------------
// Block b owns pattern b. Early-exit if no sample has pattern b (generic x has
// only 4 sign patterns). Otherwise: fp16 h0 slab -> LDS, layers 1-3 from
// 12-B/neuron streams (regs ping-pong one layer ahead), class sums from
// layer-3 registers, scatter (r0,r1) to samples with pats[n]==b.
// upd (reference 2nd pass) fires only if r0/r1 is exactly 0.0/1.0 ->
// block-locally detectable; never-taken slow path runs the exact full logic.
__global__ __launch_bounds__(1024) void table_scatter(
    const uint2* __restrict__ cf16, const unsigned* __restrict__ pidx,
    const __half* __restrict__ h0f16, const unsigned char* __restrict__ pats,
    const unsigned* __restrict__ maskp,
    const float* __restrict__ x, float* __restrict__ out) {
    __shared__ float h0[KN];
    __shared__ float h1[KN];
    __shared__ float red[34];
    __shared__ float tbl[32];
    __shared__ unsigned smask;
    const int pat = blockIdx.x;
    const int tid = threadIdx.x;

    // Pattern-occupancy mask (64 uints, OR-reduced by wave 0).
    if (tid < 64) {
        unsigned m = maskp[tid];
        #pragma unroll
        for (int off = 32; off > 0; off >>= 1) m |= __shfl_xor(m, off, 64);
        if (tid == 0) smask = m;
    }
    __syncthreads();
    if (!((smask >> pat) & 1u)) return;   // no samples with my pattern

    // h0 slab (fp16, 8 KB) + layer-1/2 desc loads issued together.
    uint2 cB[4], cA[4];
    unsigned xB[4], xA[4];
    #pragma unroll
    for (int i = 0; i < 4; ++i) {
        int k = tid + i * 1024;
        cB[i] = cf16[KN + k];      xB[i] = pidx[KN + k];       // layer 1
        cA[i] = cf16[2 * KN + k];  xA[i] = pidx[2 * KN + k];   // layer 2
    }
    {
        uint2 hv = ((const uint2*)(h0f16 + pat * KN))[tid];    // 4 halfs
        float2 lo = __half22float2(*(__half2*)&hv.x);
        float2 hi = __half22float2(*(__half2*)&hv.y);
        int k = tid * 4;
        h0[k + 0] = lo.x; h0[k + 1] = lo.y;
        h0[k + 2] = hi.x; h0[k + 3] = hi.y;
    }
    __syncthreads();

    // Layer 1: h0 -> h1; prefetch layer 3 into (cB,xB).
    #pragma unroll
    for (int i = 0; i < 4; ++i) {
        int k = tid + i * 1024;
        h1[k] = neuron2(cB[i], h0[xB[i] & 0xffff], h0[xB[i] >> 16]);
        cB[i] = cf16[3 * KN + k];
        xB[i] = pidx[3 * KN + k];
    }
    __syncthreads();
    // Layer 2: h1 -> h0.
    #pragma unroll
    for (int i = 0; i < 4; ++i) {
        int k = tid + i * 1024;
        h0[k] = neuron2(cA[i], h1[xA[i] & 0xffff], h1[xA[i] >> 16]);
    }
    __syncthreads();
    // Layer 3: straight to class partial sums (k < 2048 -> class 0).
    float s0 = 0.0f, s1 = 0.0f;
    #pragma unroll
    for (int i = 0; i < 4; ++i) {
        float o = neuron2(cB[i], h0[xB[i] & 0xffff], h0[xB[i] >> 16]);
        if (i < 2) s0 += o; else s1 += o;
    }
    #pragma unroll
    for (int off = 32; off > 0; off >>= 1) {
        s0 += __shfl_down(s0, off, 64);
        s1 += __shfl_down(s1, off, 64);
    }
    int wid = tid >> 6, lane = tid & 63;
    if (lane == 0) { red[wid] = s0; red[16 + wid] = s1; }
    __syncthreads();
    if (tid == 0) {
        float t0 = 0.0f, t1 = 0.0f;
        #pragma unroll
        for (int wq = 0; wq < 16; ++wq) { t0 += red[wq]; t1 += red[16 + wq]; }
        red[32] = t0; red[33] = t1;
    }
    __syncthreads();
    float r0 = red[32], r1 = red[33];

    bool slow = (r0 == 0.0f) || (r0 == 1.0f) || (r1 == 0.0f) || (r1 == 1.0f);
    if (!slow) {
        // upd never fires -> p1 == p0 -> out = (r0, r1) where pats[n] == pat.
        uint4 pv = ((const uint4*)pats)[tid];
        int base = tid * 16;
        unsigned wv[4] = { pv.x, pv.y, pv.z, pv.w };
        #pragma unroll
        for (int wq = 0; wq < 4; ++wq) {
            #pragma unroll
            for (int b = 0; b < 4; ++b) {
                if (((wv[wq] >> (8 * b)) & 0xffu) == (unsigned)pat) {
                    int n = base + wq * 4 + b;
                    ((float2*)out)[n] = make_float2(r0, r1);
                }
            }
        }
    } else {
        // Never taken in practice: full 16-entry table + exact update logic.
        for (int pp = 0; pp < 16; ++pp) {
            float q0, q1;
            eval_full(pp, cf16, pidx, h0f16, h0, h1, red, tid, q0, q1);
            if (tid == 0) { tbl[2 * pp] = q0; tbl[2 * pp + 1] = q1; }
        }
        __syncthreads();
        for (int n = tid; n < NSAMP; n += 1024) {
            if (pats[n] != (unsigned char)pat) continue;
            float2 xv = ((const float2*)x)[n];
            float mx[4] = { xv.x, xv.y, -xv.x, -xv.y };
            float ivf[4];
            int p0 = 0;
            #pragma unroll
            for (int i = 0; i < 4; ++i) {
                int b = mx[i] > 0.0f;
                ivf[i] = (float)b;
                p0 |= b << i;
            }
            float q0 = tbl[2 * p0], q1 = tbl[2 * p0 + 1];
            int lastl = (q1 > q0) ? 1 : 0;            // argmax, tie -> 0
            float thresh = lastl ? 0.5f : -0.5f;
            int p1 = 0;
            #pragma unroll
            for (int i = 0; i < 4; ++i) {
                bool upd = (ivf[i] == q0) || (ivf[i] == q1);  // any(flags==0)
                int bit = upd ? (int)(mx[i] > thresh) : (int)ivf[i];
                p1 |= bit << i;
            }
            ((float2*)out)[n] = make_float2(tbl[2 * p1], tbl[2 * p1 + 1]);
        }
    }
}

extern "C" void kernel_launch(void* const* d_in, const int* in_sizes, int n_in,
                              void* d_out, int out_size, void* d_ws, size_t ws_size,
                              hipStream_t stream) {
    const float* x   = (const float*)d_in[0];
    const float* w0  = (const float*)d_in[1];
    const float* wsG = (const float*)d_in[2];
    const int* ia0   = (const int*)d_in[3];
    const int* ib0   = (const int*)d_in[4];
    const int* ia    = (const int*)d_in[5];
    const int* ib    = (const int*)d_in[6];

    uint2* cf16         = (uint2*)d_ws;                       // 128 KB
    unsigned* pidx      = (unsigned*)((char*)d_ws + 131072);  //  64 KB
    __half* h0f16       = (__half*)((char*)d_ws + 196608);    // 128 KB
    unsigned char* pats = (unsigned char*)d_ws + 327680;      //  16 KB
    unsigned* maskp     = (unsigned*)((char*)d_ws + 344064);  // 256 B

    prep<<<128, 256, 0, stream>>>(w0, wsG, ia0, ib0, ia, ib, x,
                                  cf16, pidx, h0f16, pats, maskp);
    table_scatter<<<16, 1024, 0, stream>>>(cf16, pidx, h0f16, pats, maskp, x,
                                           (float*)d_out);
}

// Round 13
// 17.691 us; speedup vs baseline: 1.0248x; 1.0248x over previous
//
#include <hip/hip_runtime.h>
#include <hip/hip_fp16.h>

#define KN 4096
#define NSAMP 16384

// d_ws layout:
//   cf16  : uint2[16384]  @ 0        (128 KB)  4xfp16 coeffs per neuron (layers 1-3 used)
//   pidx  : uint [16384]  @ 131072   ( 64 KB)  ia | (ib<<16)
//   h0all : float[65536]  @ 196608   (256 KB)  layer-0 output for all 16 patterns
//   pats  : uchar[16384]  @ 458752   ( 16 KB)  p0 pattern byte per sample
//   maskp : uint [64]     @ 475136   (256 B)   per-prep-block OR of (1<<p0)

__device__ __forceinline__ void softmax16(const float* __restrict__ wp,
                                          float& c0, float& ca, float& cb, float& cab) {
    const float4* wr = (const float4*)wp;
    float4 v0 = wr[0], v1 = wr[1], v2 = wr[2], v3 = wr[3];
    // weights ~ N(0,1): expf cannot overflow -> skip max-subtract.
    float e0 = __expf(v0.x), e1 = __expf(v0.y), e2 = __expf(v0.z), e3 = __expf(v0.w);
    float e4 = __expf(v1.x), e5 = __expf(v1.y), e6 = __expf(v1.z), e7 = __expf(v1.w);
    float e8 = __expf(v2.x), e9 = __expf(v2.y), e10 = __expf(v2.z), e11 = __expf(v2.w);
    float e12 = __expf(v3.x), e13 = __expf(v3.y), e14 = __expf(v3.z), e15 = __expf(v3.w);
    float s = ((e0 + e1) + (e2 + e3)) + ((e4 + e5) + (e6 + e7))
            + ((e8 + e9) + (e10 + e11)) + ((e12 + e13) + (e14 + e15));
    float can  = ((e2 + e3) + (e6 + e7)) - ((e8 + e9) + (e12 + e13));
    float cbn  = ((e4 + e5) + (e6 + e7)) - ((e8 + e9) + (e10 + e11));
    float cabn = (e1 - e2) - (e4 + e7) - 2.0f * e6 + (e8 + e11) + 2.0f * e9
               + (e13 - e14);
    float c0n  = ((e8 + e9) + (e10 + e11)) + ((e12 + e13) + (e14 + e15));
    float inv = 1.0f / s;
    c0 = c0n * inv; ca = can * inv; cb = cbn * inv; cab = cabn * inv;
}

// ---------------- Node 1: prep (368 blocks x 256) ----------------
// bid in [0,48):    layers 1-3 neuron coeffs (fp16x4) + packed indices.
// bid in [48,304):  h0all[pat][k] for all 16 patterns (redundant softmax; wide).
// bid in [304,368): pats[n] = p0 sign pattern + per-block occupancy OR-mask.
__global__ __launch_bounds__(256) void prep(
    const float* __restrict__ w0, const float* __restrict__ wsG,
    const int* __restrict__ ia0, const int* __restrict__ ib0,
    const int* __restrict__ ia, const int* __restrict__ ib,
    const float* __restrict__ x,
    uint2* __restrict__ cf16, unsigned* __restrict__ pidx,
    float* __restrict__ h0all, unsigned char* __restrict__ pats,
    unsigned* __restrict__ maskp) {
    const int bid = blockIdx.x, tid = threadIdx.x;
    if (bid < 48) {
        int g = KN + bid * 256 + tid;          // g in [4096, 16384)
        int layer = g >> 12;                   // 1..3
        int k = g & 4095;
        float c0, ca, cb, cab;
        softmax16(wsG + ((size_t)(layer - 1) * KN + k) * 16, c0, ca, cb, cab);
        __half2 p01 = __floats2half2_rn(c0, ca);
        __half2 p23 = __floats2half2_rn(cb, cab);
        uint2 c;
        c.x = *(unsigned*)&p01;
        c.y = *(unsigned*)&p23;
        cf16[g] = c;
        pidx[g] = (unsigned)ia[(layer - 1) * KN + k]
                | ((unsigned)ib[(layer - 1) * KN + k] << 16);
    } else if (bid < 304) {
        int j = (bid - 48) * 256 + tid;        // j in [0, 65536)
        int pat = j >> 12, k = j & 4095;
        float c0, ca, cb, cab;
        softmax16(w0 + (size_t)k * 16, c0, ca, cb, cab);
        float a = (float)((pat >> ia0[k]) & 1);
        float b = (float)((pat >> ib0[k]) & 1);
        h0all[j] = c0 + ca * a + cb * b + cab * (a * b);
    } else {
        int n = (bid - 304) * 256 + tid;
        float2 xv = ((const float2*)x)[n];
        int p0 = (int)(xv.x > 0.0f) | ((int)(xv.y > 0.0f) << 1)
               | ((int)(-xv.x > 0.0f) << 2) | ((int)(-xv.y > 0.0f) << 3);
        pats[n] = (unsigned char)p0;
        // Block OR-mask of patterns present (plain stores, rewritten each call).
        __shared__ unsigned sm[4];
        unsigned m = 1u << p0;
        #pragma unroll
        for (int off = 32; off > 0; off >>= 1) m |= __shfl_xor(m, off, 64);
        int wid = tid >> 6, lane = tid & 63;
        if (lane == 0) sm[wid] = m;
        __syncthreads();
        if (tid == 0) maskp[bid - 304] = sm[0] | sm[1] | sm[2] | sm[3];
    }
}

__device__ __forceinline__ float neuron2(uint2 c, float a, float b) {
    float2 c01 = __half22float2(*(__half2*)&c.x);   // (c0, ca)
    float2 c23 = __half22float2(*(__half2*)&c.y);   // (cb, cab)
    return c01.x + c01.y * a + c23.x * b + c23.y * (a * b);
}

// Slow-path helper (never taken in practice): full network eval for pattern pp.
__device__ void eval_full(int pp, const uint2* __restrict__ cf16,
                          const unsigned* __restrict__ pidx,
                          const float* __restrict__ h0all,
                          float* h0, float* h1, float* red, int tid,
                          float& r0, float& r1) {
    #pragma unroll
    for (int i = 0; i < 4; ++i) {
        int k = tid + i * 1024;
        h0[k] = h0all[pp * KN + k];
    }
    __syncthreads();
    for (int l = 1; l <= 3; ++l) {
        const float* src = (l & 1) ? h0 : h1;
        float* dst = (l & 1) ? h1 : h0;
        #pragma unroll
        for (int i = 0; i < 4; ++i) {
            int k = tid + i * 1024;
            unsigned xi = pidx[l * KN + k];
            dst[k] = neuron2(cf16[l * KN + k], src[xi & 0xffff], src[xi >> 16]);
        }
        __syncthreads();
    }
    float s0 = h1[tid] + h1[tid + 1024];
    float s1 = h1[tid + 2048] + h1[tid + 3072];
    #pragma unroll
    for (int off = 32; off > 0; off >>= 1) {
        s0 += __shfl_down(s0, off, 64);
        s1 += __shfl_down(s1, off, 64);
    }
    int wid = tid >> 6, lane = tid & 63;
    if (lane == 0) { red[wid] = s0; red[16 + wid] = s1; }
    __syncthreads();
    if (tid == 0) {
        float t0 = 0.0f, t1 = 0.0f;
        #pragma unroll
        for (int wq = 0; wq < 16; ++wq) { t0 += red[wq]; t1 += red[16 + wq]; }
        red[32] = t0; red[33] = t1;
    }
    __syncthreads();
    r0 = red[32]; r1 = red[33];
    __syncthreads();
}

// ---------------- Node 2: per-pattern net (layers 1-3) + scatter ----------------
// Block b owns pattern b. Early-exit if no sample has pattern b (generic x has
// only 4 sign patterns; exit only when the table entry is unobservable).
// Otherwise identical to R11: h0 slab -> LDS, layers 1-3 from 12-B/neuron
// streams (regs ping-pong one layer ahead), class sums from layer-3 registers,
// scatter (r0,r1) to samples with pats[n]==b. upd (reference 2nd pass) can
// only fire if r0/r1 is exactly 0.0/1.0 -> block-locally detectable;
// never-taken slow path runs the exact full reference logic.
__global__ __launch_bounds__(1024) void table_scatter(
    const uint2* __restrict__ cf16, const unsigned* __restrict__ pidx,
    const float* __restrict__ h0all, const unsigned char* __restrict__ pats,
    const unsigned* __restrict__ maskp,
    const float* __restrict__ x, float* __restrict__ out) {
    __shared__ float h0[KN];
    __shared__ float h1[KN];
    __shared__ float red[34];
    __shared__ float tbl[32];
    __shared__ unsigned smask;
    const int pat = blockIdx.x;
    const int tid = threadIdx.x;

    // Pattern-occupancy mask (64 uints, OR-reduced by wave 0).
    if (tid < 64) {
        unsigned m = maskp[tid];
        #pragma unroll
        for (int off = 32; off > 0; off >>= 1) m |= __shfl_xor(m, off, 64);
        if (tid == 0) smask = m;
    }
    __syncthreads();
    if (!((smask >> pat) & 1u)) return;   // no samples with my pattern

    // Issue layer-1 + layer-2 descriptor loads and the h0 slab together.
    uint2 cB[4], cA[4];
    unsigned xB[4], xA[4];
    #pragma unroll
    for (int i = 0; i < 4; ++i) {
        int k = tid + i * 1024;
        cB[i] = cf16[KN + k];      xB[i] = pidx[KN + k];       // layer 1
        cA[i] = cf16[2 * KN + k];  xA[i] = pidx[2 * KN + k];   // layer 2
    }
    #pragma unroll
    for (int i = 0; i < 4; ++i) {
        int k = tid + i * 1024;
        h0[k] = h0all[pat * KN + k];
    }
    __syncthreads();

    // Layer 1: h0 -> h1; prefetch layer 3 into (cB,xB).
    #pragma unroll
    for (int i = 0; i < 4; ++i) {
        int k = tid + i * 1024;
        h1[k] = neuron2(cB[i], h0[xB[i] & 0xffff], h0[xB[i] >> 16]);
        cB[i] = cf16[3 * KN + k];
        xB[i] = pidx[3 * KN + k];
    }
    __syncthreads();
    // Layer 2: h1 -> h0.
    #pragma unroll
    for (int i = 0; i < 4; ++i) {
        int k = tid + i * 1024;
        h0[k] = neuron2(cA[i], h1[xA[i] & 0xffff], h1[xA[i] >> 16]);
    }
    __syncthreads();
    // Layer 3: straight to class partial sums (k < 2048 -> class 0).
    float s0 = 0.0f, s1 = 0.0f;
    #pragma unroll
    for (int i = 0; i < 4; ++i) {
        float o = neuron2(cB[i], h0[xB[i] & 0xffff], h0[xB[i] >> 16]);
        if (i < 2) s0 += o; else s1 += o;
    }
    #pragma unroll
    for (int off = 32; off > 0; off >>= 1) {
        s0 += __shfl_down(s0, off, 64);
        s1 += __shfl_down(s1, off, 64);
    }
    int wid = tid >> 6, lane = tid & 63;
    if (lane == 0) { red[wid] = s0; red[16 + wid] = s1; }
    __syncthreads();
    if (tid == 0) {
        float t0 = 0.0f, t1 = 0.0f;
        #pragma unroll
        for (int wq = 0; wq < 16; ++wq) { t0 += red[wq]; t1 += red[16 + wq]; }
        red[32] = t0; red[33] = t1;
    }
    __syncthreads();
    float r0 = red[32], r1 = red[33];

    bool slow = (r0 == 0.0f) || (r0 == 1.0f) || (r1 == 0.0f) || (r1 == 1.0f);
    if (!slow) {
        // upd never fires -> p1 == p0 -> out = (r0, r1) where pats[n] == pat.
        uint4 pv = ((const uint4*)pats)[tid];
        int base = tid * 16;
        unsigned wv[4] = { pv.x, pv.y, pv.z, pv.w };
        #pragma unroll
        for (int wq = 0; wq < 4; ++wq) {
            #pragma unroll
            for (int b = 0; b < 4; ++b) {
                if (((wv[wq] >> (8 * b)) & 0xffu) == (unsigned)pat) {
                    int n = base + wq * 4 + b;
                    ((float2*)out)[n] = make_float2(r0, r1);
                }
            }
        }
    } else {
        // Never taken in practice: full 16-entry table + exact update logic.
        for (int pp = 0; pp < 16; ++pp) {
            float q0, q1;
            eval_full(pp, cf16, pidx, h0all, h0, h1, red, tid, q0, q1);
            if (tid == 0) { tbl[2 * pp] = q0; tbl[2 * pp + 1] = q1; }
        }
        __syncthreads();
        for (int n = tid; n < NSAMP; n += 1024) {
            if (pats[n] != (unsigned char)pat) continue;
            float2 xv = ((const float2*)x)[n];
            float mx[4] = { xv.x, xv.y, -xv.x, -xv.y };
            float ivf[4];
            int p0 = 0;
            #pragma unroll
            for (int i = 0; i < 4; ++i) {
                int b = mx[i] > 0.0f;
                ivf[i] = (float)b;
                p0 |= b << i;
            }
            float q0 = tbl[2 * p0], q1 = tbl[2 * p0 + 1];
            int lastl = (q1 > q0) ? 1 : 0;            // argmax, tie -> 0
            float thresh = lastl ? 0.5f : -0.5f;
            int p1 = 0;
            #pragma unroll
            for (int i = 0; i < 4; ++i) {
                bool upd = (ivf[i] == q0) || (ivf[i] == q1);  // any(flags==0)
                int bit = upd ? (int)(mx[i] > thresh) : (int)ivf[i];
                p1 |= bit << i;
            }
            ((float2*)out)[n] = make_float2(tbl[2 * p1], tbl[2 * p1 + 1]);
        }
    }
}

extern "C" void kernel_launch(void* const* d_in, const int* in_sizes, int n_in,
                              void* d_out, int out_size, void* d_ws, size_t ws_size,
                              hipStream_t stream) {
    const float* x   = (const float*)d_in[0];
    const float* w0  = (const float*)d_in[1];
    const float* wsG = (const float*)d_in[2];
    const int* ia0   = (const int*)d_in[3];
    const int* ib0   = (const int*)d_in[4];
    const int* ia    = (const int*)d_in[5];
    const int* ib    = (const int*)d_in[6];

    uint2* cf16         = (uint2*)d_ws;                          // 128 KB
    unsigned* pidx      = (unsigned*)((char*)d_ws + 131072);     //  64 KB
    float* h0all        = (float*)((char*)d_ws + 196608);        // 256 KB
    unsigned char* pats = (unsigned char*)d_ws + 458752;         //  16 KB
    unsigned* maskp     = (unsigned*)((char*)d_ws + 475136);     // 256 B

    prep<<<368, 256, 0, stream>>>(w0, wsG, ia0, ib0, ia, ib, x,
                                  cf16, pidx, h0all, pats, maskp);
    table_scatter<<<16, 1024, 0, stream>>>(cf16, pidx, h0all, pats, maskp, x,
                                           (float*)d_out);
}

// Round 14
// 17.195 us; speedup vs baseline: 1.0543x; 1.0289x over previous
//
#include <hip/hip_runtime.h>
#include <hip/hip_fp16.h>

#define KN 4096
#define NSAMP 16384

// d_ws layout:
//   cf16  : uint2[16384]  @ 0        (128 KB)  4xfp16 coeffs per neuron (layers 1-3 used)
//   pidx  : uint [16384]  @ 131072   ( 64 KB)  ia | (ib<<16)
//   h0all : float[65536]  @ 196608   (256 KB)  layer-0 output for all 16 patterns
//   pats  : uchar[16384]  @ 458752   ( 16 KB)  p0 pattern byte per sample

__device__ __forceinline__ void softmax16(const float* __restrict__ wp,
                                          float& c0, float& ca, float& cb, float& cab) {
    const float4* wr = (const float4*)wp;
    float4 v0 = wr[0], v1 = wr[1], v2 = wr[2], v3 = wr[3];
    // weights ~ N(0,1): expf cannot overflow -> skip max-subtract.
    float e0 = __expf(v0.x), e1 = __expf(v0.y), e2 = __expf(v0.z), e3 = __expf(v0.w);
    float e4 = __expf(v1.x), e5 = __expf(v1.y), e6 = __expf(v1.z), e7 = __expf(v1.w);
    float e8 = __expf(v2.x), e9 = __expf(v2.y), e10 = __expf(v2.z), e11 = __expf(v2.w);
    float e12 = __expf(v3.x), e13 = __expf(v3.y), e14 = __expf(v3.z), e15 = __expf(v3.w);
    float s = ((e0 + e1) + (e2 + e3)) + ((e4 + e5) + (e6 + e7))
            + ((e8 + e9) + (e10 + e11)) + ((e12 + e13) + (e14 + e15));
    float can  = ((e2 + e3) + (e6 + e7)) - ((e8 + e9) + (e12 + e13));
    float cbn  = ((e4 + e5) + (e6 + e7)) - ((e8 + e9) + (e10 + e11));
    float cabn = (e1 - e2) - (e4 + e7) - 2.0f * e6 + (e8 + e11) + 2.0f * e9
               + (e13 - e14);
    float c0n  = ((e8 + e9) + (e10 + e11)) + ((e12 + e13) + (e14 + e15));
    float inv = 1.0f / s;
    c0 = c0n * inv; ca = can * inv; cb = cbn * inv; cab = cabn * inv;
}

// ---------------- Node 1: prep (368 blocks x 256) ----------------
// bid in [0,48):    layers 1-3 neuron coeffs (fp16x4) + packed indices.
// bid in [48,304):  h0all[pat][k] for all 16 patterns (redundant softmax; wide).
// bid in [304,368): pats[n] = p0 sign-bit pattern of sample n.
__global__ __launch_bounds__(256) void prep(
    const float* __restrict__ w0, const float* __restrict__ wsG,
    const int* __restrict__ ia0, const int* __restrict__ ib0,
    const int* __restrict__ ia, const int* __restrict__ ib,
    const float* __restrict__ x,
    uint2* __restrict__ cf16, unsigned* __restrict__ pidx,
    float* __restrict__ h0all, unsigned char* __restrict__ pats) {
    const int bid = blockIdx.x, tid = threadIdx.x;
    if (bid < 48) {
        int g = KN + bid * 256 + tid;          // g in [4096, 16384)
        int layer = g >> 12;                   // 1..3
        int k = g & 4095;
        float c0, ca, cb, cab;
        softmax16(wsG + ((size_t)(layer - 1) * KN + k) * 16, c0, ca, cb, cab);
        __half2 p01 = __floats2half2_rn(c0, ca);
        __half2 p23 = __floats2half2_rn(cb, cab);
        uint2 c;
        c.x = *(unsigned*)&p01;
        c.y = *(unsigned*)&p23;
        cf16[g] = c;
        pidx[g] = (unsigned)ia[(layer - 1) * KN + k]
                | ((unsigned)ib[(layer - 1) * KN + k] << 16);
    } else if (bid < 304) {
        int j = (bid - 48) * 256 + tid;        // j in [0, 65536)
        int pat = j >> 12, k = j & 4095;
        float c0, ca, cb, cab;
        softmax16(w0 + (size_t)k * 16, c0, ca, cb, cab);
        float a = (float)((pat >> ia0[k]) & 1);
        float b = (float)((pat >> ib0[k]) & 1);
        h0all[j] = c0 + ca * a + cb * b + cab * (a * b);
    } else {
        int n = (bid - 304) * 256 + tid;
        float2 xv = ((const float2*)x)[n];
        int p0 = (int)(xv.x > 0.0f) | ((int)(xv.y > 0.0f) << 1)
               | ((int)(-xv.x > 0.0f) << 2) | ((int)(-xv.y > 0.0f) << 3);
        pats[n] = (unsigned char)p0;
    }
}

__device__ __forceinline__ float neuron2(uint2 c, float a, float b) {
    float2 c01 = __half22float2(*(__half2*)&c.x);   // (c0, ca)
    float2 c23 = __half22float2(*(__half2*)&c.y);   // (cb, cab)
    return c01.x + c01.y * a + c23.x * b + c23.y * (a * b);
}

// Slow-path helper (never taken in practice): full network eval for pattern pp.
__device__ void eval_full(int pp, const uint2* __restrict__ cf16,
                          const unsigned* __restrict__ pidx,
                          const float* __restrict__ h0all,
                          float* h0, float* h1, float* red, int tid,
                          float& r0, float& r1) {
    #pragma unroll
    for (int i = 0; i < 4; ++i) {
        int k = tid + i * 1024;
        h0[k] = h0all[pp * KN + k];
    }
    __syncthreads();
    for (int l = 1; l <= 3; ++l) {
        const float* src = (l & 1) ? h0 : h1;
        float* dst = (l & 1) ? h1 : h0;
        #pragma unroll
        for (int i = 0; i < 4; ++i) {
            int k = tid + i * 1024;
            unsigned xi = pidx[l * KN + k];
            dst[k] = neuron2(cf16[l * KN + k], src[xi & 0xffff], src[xi >> 16]);
        }
        __syncthreads();
    }
    float s0 = h1[tid] + h1[tid + 1024];
    float s1 = h1[tid + 2048] + h1[tid + 3072];
    #pragma unroll
    for (int off = 32; off > 0; off >>= 1) {
        s0 += __shfl_down(s0, off, 64);
        s1 += __shfl_down(s1, off, 64);
    }
    int wid = tid >> 6, lane = tid & 63;
    if (lane == 0) { red[wid] = s0; red[16 + wid] = s1; }
    __syncthreads();
    if (tid == 0) {
        float t0 = 0.0f, t1 = 0.0f;
        #pragma unroll
        for (int wq = 0; wq < 16; ++wq) { t0 += red[wq]; t1 += red[16 + wq]; }
        red[32] = t0; red[33] = t1;
    }
    __syncthreads();
    r0 = red[32]; r1 = red[33];
    __syncthreads();
}

// ---------------- Node 2: per-pattern net (layers 1-3) + scatter ----------------
// Block b owns pattern b: loads its precomputed h0 slab (16 KB), runs layers
// 1-3 from 12-B/neuron streams (regs ping-pong one layer ahead), sums classes
// from layer-3 registers, then scatters (r0,r1) to samples with pats[n]==b.
// upd (reference 2nd pass) can only fire if r0/r1 is exactly 0.0/1.0 ->
// block-locally detectable; never-taken slow path runs the exact full logic.
__global__ __launch_bounds__(1024) void table_scatter(
    const uint2* __restrict__ cf16, const unsigned* __restrict__ pidx,
    const float* __restrict__ h0all, const unsigned char* __restrict__ pats,
    const float* __restrict__ x, float* __restrict__ out) {
    __shared__ float h0[KN];
    __shared__ float h1[KN];
    __shared__ float red[34];
    __shared__ float tbl[32];
    const int pat = blockIdx.x;
    const int tid = threadIdx.x;

    // Issue layer-1 + layer-2 descriptor loads and the h0 slab together.
    uint2 cB[4], cA[4];
    unsigned xB[4], xA[4];
    #pragma unroll
    for (int i = 0; i < 4; ++i) {
        int k = tid + i * 1024;
        cB[i] = cf16[KN + k];      xB[i] = pidx[KN + k];       // layer 1
        cA[i] = cf16[2 * KN + k];  xA[i] = pidx[2 * KN + k];   // layer 2
    }
    #pragma unroll
    for (int i = 0; i < 4; ++i) {
        int k = tid + i * 1024;
        h0[k] = h0all[pat * KN + k];
    }
    __syncthreads();

    // Layer 1: h0 -> h1; prefetch layer 3 into (cB,xB).
    #pragma unroll
    for (int i = 0; i < 4; ++i) {
        int k = tid + i * 1024;
        h1[k] = neuron2(cB[i], h0[xB[i] & 0xffff], h0[xB[i] >> 16]);
        cB[i] = cf16[3 * KN + k];
        xB[i] = pidx[3 * KN + k];
    }
    __syncthreads();
    // Layer 2: h1 -> h0.
    #pragma unroll
    for (int i = 0; i < 4; ++i) {
        int k = tid + i * 1024;
        h0[k] = neuron2(cA[i], h1[xA[i] & 0xffff], h1[xA[i] >> 16]);
    }
    __syncthreads();
    // Layer 3: straight to class partial sums (k < 2048 -> class 0).
    float s0 = 0.0f, s1 = 0.0f;
    #pragma unroll
    for (int i = 0; i < 4; ++i) {
        float o = neuron2(cB[i], h0[xB[i] & 0xffff], h0[xB[i] >> 16]);
        if (i < 2) s0 += o; else s1 += o;
    }
    #pragma unroll
    for (int off = 32; off > 0; off >>= 1) {
        s0 += __shfl_down(s0, off, 64);
        s1 += __shfl_down(s1, off, 64);
    }
    int wid = tid >> 6, lane = tid & 63;
    if (lane == 0) { red[wid] = s0; red[16 + wid] = s1; }
    __syncthreads();
    if (tid == 0) {
        float t0 = 0.0f, t1 = 0.0f;
        #pragma unroll
        for (int wq = 0; wq < 16; ++wq) { t0 += red[wq]; t1 += red[16 + wq]; }
        red[32] = t0; red[33] = t1;
    }
    __syncthreads();
    float r0 = red[32], r1 = red[33];

    bool slow = (r0 == 0.0f) || (r0 == 1.0f) || (r1 == 0.0f) || (r1 == 1.0f);
    if (!slow) {
        // upd never fires -> p1 == p0 -> out = (r0, r1) where pats[n] == pat.
        uint4 pv = ((const uint4*)pats)[tid];
        int base = tid * 16;
        unsigned wv[4] = { pv.x, pv.y, pv.z, pv.w };
        #pragma unroll
        for (int wq = 0; wq < 4; ++wq) {
            #pragma unroll
            for (int b = 0; b < 4; ++b) {
                if (((wv[wq] >> (8 * b)) & 0xffu) == (unsigned)pat) {
                    int n = base + wq * 4 + b;
                    ((float2*)out)[n] = make_float2(r0, r1);
                }
            }
        }
    } else {
        // Never taken in practice: full 16-entry table + exact update logic.
        for (int pp = 0; pp < 16; ++pp) {
            float q0, q1;
            eval_full(pp, cf16, pidx, h0all, h0, h1, red, tid, q0, q1);
            if (tid == 0) { tbl[2 * pp] = q0; tbl[2 * pp + 1] = q1; }
        }
        __syncthreads();
        for (int n = tid; n < NSAMP; n += 1024) {
            if (pats[n] != (unsigned char)pat) continue;
            float2 xv = ((const float2*)x)[n];
            float mx[4] = { xv.x, xv.y, -xv.x, -xv.y };
            float ivf[4];
            int p0 = 0;
            #pragma unroll
            for (int i = 0; i < 4; ++i) {
                int b = mx[i] > 0.0f;
                ivf[i] = (float)b;
                p0 |= b << i;
            }
            float q0 = tbl[2 * p0], q1 = tbl[2 * p0 + 1];
            int lastl = (q1 > q0) ? 1 : 0;            // argmax, tie -> 0
            float thresh = lastl ? 0.5f : -0.5f;
            int p1 = 0;
            #pragma unroll
            for (int i = 0; i < 4; ++i) {
                bool upd = (ivf[i] == q0) || (ivf[i] == q1);  // any(flags==0)
                int bit = upd ? (int)(mx[i] > thresh) : (int)ivf[i];
                p1 |= bit << i;
            }
            ((float2*)out)[n] = make_float2(tbl[2 * p1], tbl[2 * p1 + 1]);
        }
    }
}

extern "C" void kernel_launch(void* const* d_in, const int* in_sizes, int n_in,
                              void* d_out, int out_size, void* d_ws, size_t ws_size,
                              hipStream_t stream) {
    const float* x   = (const float*)d_in[0];
    const float* w0  = (const float*)d_in[1];
    const float* wsG = (const float*)d_in[2];
    const int* ia0   = (const int*)d_in[3];
    const int* ib0   = (const int*)d_in[4];
    const int* ia    = (const int*)d_in[5];
    const int* ib    = (const int*)d_in[6];

    uint2* cf16         = (uint2*)d_ws;                          // 128 KB
    unsigned* pidx      = (unsigned*)((char*)d_ws + 131072);     //  64 KB
    float* h0all        = (float*)((char*)d_ws + 196608);        // 256 KB
    unsigned char* pats = (unsigned char*)d_ws + 458752;         //  16 KB

    prep<<<368, 256, 0, stream>>>(w0, wsG, ia0, ib0, ia, ib, x,
                                  cf16, pidx, h0all, pats);
    table_scatter<<<16, 1024, 0, stream>>>(cf16, pidx, h0all, pats, x,
                                           (float*)d_out);
}